// Round 2
// baseline (1073.157 us; speedup 1.0000x reference)
//
#include <hip/hip_runtime.h>

typedef __attribute__((ext_vector_type(8))) __bf16 bf16x8;
typedef __attribute__((ext_vector_type(4))) float f32x4;

#define GM 4096
#define GN 16384
#define GK 1024
#define TOPK 32
#define DELTA 0.04f

// ---------- helpers ----------
__device__ __forceinline__ unsigned short f2bf(float f) {
  union { float f; unsigned int u; } c; c.f = f;
  unsigned int u = c.u;
  u += 0x7fffu + ((u >> 16) & 1u);   // RNE
  return (unsigned short)(u >> 16);
}
__device__ __forceinline__ float bf2f(unsigned short h) {
  union { unsigned int u; float f; } c; c.u = ((unsigned int)h) << 16;
  return c.f;
}
__device__ __forceinline__ unsigned int kabs(float f) {
  union { float f; unsigned int u; } c; c.f = f;
  return c.u & 0x7fffffffu;
}
__device__ __forceinline__ float ufloat(unsigned int u) {
  union { unsigned int u; float f; } c; c.u = u;
  return c.f;
}
typedef __attribute__((address_space(3))) unsigned int lds_uint;
typedef __attribute__((address_space(1))) unsigned int glob_uint;
__device__ __forceinline__ void load_lds16(const void* g, void* l) {
  __builtin_amdgcn_global_load_lds((const glob_uint*)g, (lds_uint*)l, 16, 0, 0);
}

// ---------- fp32 -> bf16 convert ----------
__global__ __launch_bounds__(256) void f32_to_bf16(const float4* __restrict__ in,
                                                   ushort4* __restrict__ out, int n4) {
  int i = blockIdx.x * 256 + threadIdx.x;
  if (i < n4) {
    float4 v = in[i];
    ushort4 o;
    o.x = f2bf(v.x); o.y = f2bf(v.y); o.z = f2bf(v.z); o.w = f2bf(v.w);
    out[i] = o;
  }
}

// ---------- transpose W_dec (1024 x 16384 f32) -> W_decT (16384 x 1024 bf16) ----------
__global__ __launch_bounds__(256) void transpose_wdec(const float* __restrict__ Wd,
                                                      unsigned short* __restrict__ WdT) {
  __shared__ float tile[32][33];
  int h0 = blockIdx.x * 32;   // along 16384
  int i0 = blockIdx.y * 32;   // along 1024
  int tx = threadIdx.x;       // 0..31
  int ty = threadIdx.y;       // 0..7
#pragma unroll
  for (int j = 0; j < 4; j++)
    tile[ty + j * 8][tx] = Wd[(size_t)(i0 + ty + j * 8) * GN + h0 + tx];
  __syncthreads();
#pragma unroll
  for (int j = 0; j < 4; j++)
    WdT[(size_t)(h0 + ty + j * 8) * 1024 + i0 + tx] = f2bf(tile[tx][ty + j * 8]);
}

// ---------- GEMM: C[m][n] = sum_k A[m][k]*B[n][k], bf16 in, f32 out ----------
__global__ __launch_bounds__(256) void gemm_bt(const unsigned short* __restrict__ A,
                                               const unsigned short* __restrict__ B,
                                               float* __restrict__ C) {
  __shared__ __align__(16) unsigned short As[128 * 64];
  __shared__ __align__(16) unsigned short Bs[128 * 64];
  const int bx = blockIdx.x;  // N tile
  const int by = blockIdx.y;  // M tile
  const int tid = threadIdx.x;
  const int lane = tid & 63;
  const int w = tid >> 6;
  const int wm = (w >> 1) * 64;
  const int wn = (w & 1) * 64;
  const int row = lane & 15;
  const int quad = lane >> 4;
  const int sm = lane >> 3;        // 0..7
  const int sk = (lane & 7) * 8;   // 0..56

  f32x4 acc[4][4];
#pragma unroll
  for (int a = 0; a < 4; a++)
#pragma unroll
    for (int b = 0; b < 4; b++) acc[a][b] = f32x4{0.f, 0.f, 0.f, 0.f};

  const unsigned short* Ab = A + (size_t)(by * 128) * GK;
  const unsigned short* Bb = B + (size_t)(bx * 128) * GK;

  for (int kt = 0; kt < GK; kt += 64) {
#pragma unroll
    for (int i = 0; i < 4; i++) {
      int mloc = (i * 4 + w) * 8 + sm;
      load_lds16(Ab + (size_t)mloc * GK + kt + sk, &As[(i * 4 + w) * 512]);
      load_lds16(Bb + (size_t)mloc * GK + kt + sk, &Bs[(i * 4 + w) * 512]);
    }
    __syncthreads();
#pragma unroll
    for (int ks = 0; ks < 2; ks++) {
      bf16x8 af[4], bfr[4];
#pragma unroll
      for (int mi = 0; mi < 4; mi++)
        af[mi] = *(const bf16x8*)&As[(wm + mi * 16 + row) * 64 + ks * 32 + quad * 8];
#pragma unroll
      for (int ni = 0; ni < 4; ni++)
        bfr[ni] = *(const bf16x8*)&Bs[(wn + ni * 16 + row) * 64 + ks * 32 + quad * 8];
#pragma unroll
      for (int mi = 0; mi < 4; mi++)
#pragma unroll
        for (int ni = 0; ni < 4; ni++)
          acc[mi][ni] = __builtin_amdgcn_mfma_f32_16x16x32_bf16(af[mi], bfr[ni], acc[mi][ni], 0, 0, 0);
    }
    __syncthreads();
  }
  float* Cb = C + (size_t)(by * 128 + wm) * GN + bx * 128 + wn;
#pragma unroll
  for (int mi = 0; mi < 4; mi++)
#pragma unroll
    for (int ni = 0; ni < 4; ni++)
#pragma unroll
      for (int r = 0; r < 4; r++)
        Cb[(size_t)(mi * 16 + quad * 4 + r) * GN + ni * 16 + row] = acc[mi][ni][r];
}

// ---------- top-K per row with exact refinement ----------
#define CAP 512
#define RCAP 128
__global__ __launch_bounds__(256) void topk_kernel(const float* __restrict__ hpre,
                                                   const float* __restrict__ x,
                                                   const float* __restrict__ Wenc,
                                                   float* __restrict__ hsp,
                                                   float* __restrict__ hpre_out,
                                                   float* __restrict__ cval,
                                                   int* __restrict__ cidx) {
  const int b = blockIdx.x;
  const int t = threadIdx.x;
  const size_t rbase = (size_t)b * GN;
  const float4* rowv = (const float4*)(hpre + rbase);

  float4 v[16];
#pragma unroll
  for (int i = 0; i < 16; i++) v[i] = rowv[t + 256 * i];

  // phase 1: per-thread max |.| key
  unsigned int mx = 0;
#pragma unroll
  for (int i = 0; i < 16; i++) {
    unsigned int a0 = kabs(v[i].x), a1 = kabs(v[i].y), a2 = kabs(v[i].z), a3 = kabs(v[i].w);
    if (a0 > mx) mx = a0;
    if (a1 > mx) mx = a1;
    if (a2 > mx) mx = a2;
    if (a3 > mx) mx = a3;
  }
  __shared__ unsigned int maxes[256];
  __shared__ unsigned int Tlow;
  __shared__ float s_t32;
  __shared__ int cnt, rcnt;
  maxes[t] = mx;
  if (t == 0) { cnt = 0; rcnt = 0; }
  __syncthreads();

  // phase 2: rank my max among 256 maxima; rank 31 -> T (count(>=T) >= 32 guaranteed, T <= v32hat)
  int rk = 0;
  for (int j = 0; j < 256; j++) {
    unsigned int mj = maxes[j];
    rk += (mj > mx || (mj == mx && j < t)) ? 1 : 0;
  }
  if (rk == 31) Tlow = mx;
  __syncthreads();
  const float cutoff = ufloat(Tlow) - DELTA;

  // phase 3: collect candidates with |v| >= T - delta
  __shared__ float cv[CAP];
  __shared__ int ci[CAP];
#pragma unroll
  for (int i = 0; i < 16; i++) {
    int e0 = (t + 256 * i) * 4;
    float vals[4] = {v[i].x, v[i].y, v[i].z, v[i].w};
#pragma unroll
    for (int j = 0; j < 4; j++) {
      if (fabsf(vals[j]) >= cutoff) {
        int p = atomicAdd(&cnt, 1);
        if (p < CAP) { cv[p] = vals[j]; ci[p] = e0 + j; }
      }
    }
  }
  __syncthreads();
  const int C = cnt < CAP ? cnt : CAP;

  // phase 4a: rank candidates by approx |v| (desc, idx asc); record t32hat = 32nd largest approx
  for (int p = t; p < C; p += 256) {
    unsigned int kp = kabs(cv[p]);
    int ip = ci[p];
    int r = 0;
    for (int q = 0; q < C; q++) {
      unsigned int kq = kabs(cv[q]);
      r += (kq > kp || (kq == kp && ci[q] < ip)) ? 1 : 0;
    }
    if (r == 31) s_t32 = fabsf(cv[p]);
  }
  __syncthreads();

  // phase 4b: refine list = candidates with |v| >= t32hat - delta (contains true top-32 provably)
  __shared__ int rl[RCAP];
  const float rcut = s_t32 - DELTA;
  for (int p = t; p < C; p += 256) {
    if (fabsf(cv[p]) >= rcut) {
      int r = atomicAdd(&rcnt, 1);
      if (r < RCAP) rl[r] = p;
    }
  }
  // phase 5: stage x row (fp32) into LDS
  __shared__ float xs[GK];
  {
    const float4* xr = (const float4*)(x + (size_t)b * GK);
    ((float4*)xs)[t] = xr[t];
  }
  __syncthreads();
  const int rn = rcnt < RCAP ? rcnt : RCAP;

  // phase 6: exact dot (fp64 accum) for refine list
  __shared__ double ev[RCAP];
  {
    const int lane = t & 63;
    const int wv = t >> 6;
    for (int r = wv; r < rn; r += 4) {
      const float4* wrow = (const float4*)(Wenc + (size_t)ci[rl[r]] * GK);
      double s = 0.0;
#pragma unroll
      for (int j = 0; j < 4; j++) {
        float4 w4 = wrow[j * 64 + lane];
        float4 x4 = ((const float4*)xs)[j * 64 + lane];
        s += (double)w4.x * x4.x + (double)w4.y * x4.y +
             (double)w4.z * x4.z + (double)w4.w * x4.w;
      }
#pragma unroll
      for (int off = 32; off; off >>= 1) s += __shfl_down(s, off);
      if (lane == 0) ev[r] = s;
    }
  }
  __syncthreads();

  // phase 7: exact final rank among refine list (|v| desc, idx asc); set bits + cval/cidx
  __shared__ unsigned int bits[512];
  for (int j = t; j < 512; j += 256) bits[j] = 0;
  __syncthreads();
  int mysel = 0, myip = 0;
  float myval = 0.f;
  if (t < rn) {
    double vp = ev[t];
    double ap = fabs(vp);
    int ip = ci[rl[t]];
    int r = 0;
    for (int q = 0; q < rn; q++) {
      double aq = fabs(ev[q]);
      r += (aq > ap || (aq == ap && ci[rl[q]] < ip)) ? 1 : 0;
    }
    if (r < TOPK) {
      myval = (float)vp; myip = ip; mysel = 1;
      cval[b * TOPK + r] = myval;
      cidx[b * TOPK + r] = ip;
      atomicOr(&bits[ip >> 5], 1u << (ip & 31));
    }
  }
  __syncthreads();

  // phase 8: dense h_sparse write (approx values; selected positions patched in phase 9)
  float4* srow = (float4*)(hsp + rbase);
#pragma unroll
  for (int i = 0; i < 16; i++) {
    int e0 = (t + 256 * i) * 4;
    unsigned int wb = bits[e0 >> 5] >> (e0 & 31);
    float4 o;
    o.x = (wb & 1u) ? v[i].x : 0.0f;
    o.y = (wb & 2u) ? v[i].y : 0.0f;
    o.z = (wb & 4u) ? v[i].z : 0.0f;
    o.w = (wb & 8u) ? v[i].w : 0.0f;
    srow[t + 256 * i] = o;
  }
  __syncthreads();

  // phase 9: scatter exact values over selected positions (h_sparse and h_pre)
  if (mysel) {
    hsp[rbase + myip] = myval;
    hpre_out[rbase + myip] = myval;
  }
}

// ---------- recon: out[b][i] = sum_k cval[b][k] * WdT[cidx[b][k]][i] + b_dec[i] ----------
__global__ __launch_bounds__(256) void recon_kernel(const float* __restrict__ cval,
                                                    const int* __restrict__ cidx,
                                                    const unsigned short* __restrict__ WdT,
                                                    const float* __restrict__ bdec,
                                                    float* __restrict__ out) {
  const int b = blockIdx.x;
  const int t = threadIdx.x;
  __shared__ float sv[TOPK];
  __shared__ int si[TOPK];
  if (t < TOPK) { sv[t] = cval[b * TOPK + t]; si[t] = cidx[b * TOPK + t]; }
  __syncthreads();
  const int col = t * 4;
  float a0 = 0.f, a1 = 0.f, a2 = 0.f, a3 = 0.f;
#pragma unroll 8
  for (int k = 0; k < TOPK; k++) {
    float vv = sv[k];
    const ushort4 w = *(const ushort4*)&WdT[(size_t)si[k] * 1024 + col];
    a0 += vv * bf2f(w.x);
    a1 += vv * bf2f(w.y);
    a2 += vv * bf2f(w.z);
    a3 += vv * bf2f(w.w);
  }
  const float4 bd = *(const float4*)&bdec[col];
  float4 o; o.x = a0 + bd.x; o.y = a1 + bd.y; o.z = a2 + bd.z; o.w = a3 + bd.w;
  ((float4*)(out + (size_t)b * 1024))[t] = o;
}

extern "C" void kernel_launch(void* const* d_in, const int* in_sizes, int n_in,
                              void* d_out, int out_size, void* d_ws, size_t ws_size,
                              hipStream_t stream) {
  const float* x     = (const float*)d_in[0];  // 4096*1024
  const float* W_enc = (const float*)d_in[1];  // 16384*1024
  const float* W_dec = (const float*)d_in[2];  // 1024*16384
  const float* b_dec = (const float*)d_in[3];  // 1024

  float* out   = (float*)d_out;
  float* recon = out;                              // 4096*1024
  float* hsp   = out + (size_t)GM * 1024;          // 4096*16384
  float* hpre  = hsp + (size_t)GM * GN;            // 4096*16384

  char* ws = (char*)d_ws;
  unsigned short* xb  = (unsigned short*)ws;                          // 8 MB
  unsigned short* wb  = (unsigned short*)(ws + 8388608);              // 33.5 MB
  unsigned short* wdT = (unsigned short*)(ws + 8388608 + 33554432);   // 33.5 MB
  float* cval = (float*)(ws + 75497472);                              // 0.5 MB
  int*   cidx = (int*)(ws + 76021760);                                // 0.5 MB

  {
    int n4 = GM * GK / 4;
    f32_to_bf16<<<(n4 + 255) / 256, 256, 0, stream>>>((const float4*)x, (ushort4*)xb, n4);
  }
  {
    int n4 = GN * GK / 4;
    f32_to_bf16<<<(n4 + 255) / 256, 256, 0, stream>>>((const float4*)W_enc, (ushort4*)wb, n4);
  }
  transpose_wdec<<<dim3(GN / 32, 1024 / 32), dim3(32, 8), 0, stream>>>(W_dec, wdT);
  gemm_bt<<<dim3(GN / 128, GM / 128), 256, 0, stream>>>(xb, wb, hpre);
  topk_kernel<<<GM, 256, 0, stream>>>(hpre, x, W_enc, hsp, hpre, cval, cidx);
  recon_kernel<<<GM, 256, 0, stream>>>(cval, cidx, wdT, b_dec, recon);
}